// Round 4
// baseline (1816.702 us; speedup 1.0000x reference)
//
#include <hip/hip_runtime.h>
#include <cstdint>
#include <cstddef>

#define HH 128   // hidden
#define II 64    // input
#define OO 64    // output
#define G3 384   // 3*H
#define BB 64    // batch
#define TT 2048  // time
#define GX_ROWS 32

__device__ __forceinline__ float sigf(float x) { return 1.0f / (1.0f + __expf(-x)); }
__device__ __forceinline__ float tanh_fast(float x) {
    x = fminf(20.0f, fmaxf(-20.0f, x));
    float e = __expf(2.0f * x);
    return (e - 1.0f) / (e + 1.0f);
}
__device__ __forceinline__ float dot4(float4 a, float4 b) {
    return a.x * b.x + a.y * b.y + a.z * b.z + a.w * b.w;
}

// Keep a value resident in a VGPR: opaque to the optimizer, so it cannot be
// rematerialized from memory inside the loop (R3: compiler chose VGPR=60 and
// re-loaded weights from L2 every step).
#define PIN(v)  asm volatile("" : "+v"(v))
#define PIN4(v) do { PIN((v).x); PIN((v).y); PIN((v).z); PIN((v).w); } while (0)

// Quad butterfly add via DPP quad_perm — VALU pipe, NOT ds_swizzle (LDS pipe).
// xor1 = quad_perm(1,0,3,2) = 0xB1 ; xor2 = quad_perm(2,3,0,1) = 0x4E.
template <int CTRL>
__device__ __forceinline__ float dpp_add(float x) {
    return x + __int_as_float(
        __builtin_amdgcn_mov_dpp(__float_as_int(x), CTRL, 0xF, 0xF, true));
}

// ---------------- gx = x @ W_ih^T + b_ih  (parallel GEMM) ----------------
__global__ __launch_bounds__(768) void gru_gx_kernel(
        const float* __restrict__ x, const float* __restrict__ W_ih,
        const float* __restrict__ b_ih, float* __restrict__ gx) {
    __shared__ __align__(16) float sx[GX_ROWS][II];
    const int tid = threadIdx.x;
    const int g = tid >> 1;
    const int kh = tid & 1;
    const int64_t row0 = (int64_t)blockIdx.x * GX_ROWS;

    float4 w4[8];
    {
        const float4* Wp = (const float4*)(W_ih + (size_t)g * II + kh * 32);
#pragma unroll
        for (int i = 0; i < 8; ++i) w4[i] = Wp[i];
    }
#pragma unroll
    for (int i = 0; i < 8; ++i) PIN4(w4[i]);
    const float bias = b_ih[g];

    for (int i = tid; i < GX_ROWS * II; i += 768)
        ((float*)sx)[i] = x[row0 * II + i];
    __syncthreads();

#pragma unroll 4
    for (int r = 0; r < GX_ROWS; ++r) {
        const float4* sx4 = (const float4*)sx[r] + kh * 8;
        float acc = 0.0f;
#pragma unroll
        for (int i = 0; i < 8; ++i) acc += dot4(w4[i], sx4[i]);
        acc += __shfl_xor(acc, 1);
        if (kh == 0) gx[(row0 + r) * (int64_t)G3 + g] = acc + bias;
    }
}

// ---------------- recurrent scan: one block per batch, 512 threads -------
// Thread (g, c): g = tid>>2 owns h-element g via gate rows {g, g+128, g+256};
// c = tid&3 is the k-chunk [32c, 32c+32). 96 weight floats/thread, PINNED.
// Quad (4 lanes) = one h element: partial dots combined with 2 DPP quad_perm
// adds (VALU). Every lane then computes the gate update redundantly from
// registers (h_prev register-resident) -> no sC round-trip. sh double-buffered
// -> ONE barrier per step.
__global__ __launch_bounds__(512, 2) void gru_scan_kernel(
        const float* __restrict__ W_hh, const float* __restrict__ b_hh,
        const float* __restrict__ gx, float* __restrict__ hs) {
    __shared__ __align__(16) float sh[2][HH];

    const int b = blockIdx.x;
    const int tid = threadIdx.x;
    const int c = tid & 3;     // k-chunk
    const int g = tid >> 2;    // h element 0..127

    // rows g (reset), g+128 (update), g+256 (new), chunk [32c, 32c+32).
    // Pre-rotated by (j+2c)&7 so hot-loop reg indices are STATIC (R2 lesson)
    // and LDS reads land on disjoint banks across chunks.
    float4 wr[8], wz[8], wn[8];
    {
        const float4* Rr = (const float4*)(W_hh + (size_t)g * HH + c * 32);
        const float4* Rz = (const float4*)(W_hh + (size_t)(g + HH) * HH + c * 32);
        const float4* Rn = (const float4*)(W_hh + (size_t)(g + 2 * HH) * HH + c * 32);
#pragma unroll
        for (int j = 0; j < 8; ++j) {
            const int idx = (j + 2 * c) & 7;   // runtime -> ADDRESS only
            wr[j] = Rr[idx]; wz[j] = Rz[idx]; wn[j] = Rn[idx];
        }
    }
#pragma unroll
    for (int j = 0; j < 8; ++j) { PIN4(wr[j]); PIN4(wz[j]); PIN4(wn[j]); }

    const float bhr = b_hh[g];
    const float bhz = b_hh[HH + g];
    const float bhn = b_hh[2 * HH + g];

    if (tid < 2 * HH) ((float*)sh)[tid] = 0.0f;
    __syncthreads();

    const float* gxb = gx + (size_t)b * TT * G3;
    float* hsb = hs + (size_t)b * TT * HH;

    float g0 = gxb[g], g1 = gxb[HH + g], g2 = gxb[2 * HH + g];
    float hprev = 0.0f;

    for (int t = 0; t < TT; ++t) {
        const int cur = t & 1;
        // prefetch next step's gx (quad-uniform loads, L1/L2-served)
        float n0 = 0, n1 = 0, n2 = 0;
        if (t + 1 < TT) {
            const float* q = gxb + (size_t)(t + 1) * G3;
            n0 = q[g]; n1 = q[HH + g]; n2 = q[2 * HH + g];
        }

        const float4* shc = (const float4*)sh[cur] + c * 8;
        float ar = 0.0f, az = 0.0f, an = 0.0f;
#pragma unroll
        for (int j = 0; j < 8; ++j) {
            const float4 h4 = shc[(j + 2 * c) & 7];  // staggered: conflict-free
            ar += dot4(wr[j], h4);
            az += dot4(wz[j], h4);
            an += dot4(wn[j], h4);
        }
        // quad butterfly: all 4 lanes end with the full 128-k sum
        ar = dpp_add<0xB1>(ar); ar = dpp_add<0x4E>(ar);
        az = dpp_add<0xB1>(az); az = dpp_add<0x4E>(az);
        an = dpp_add<0xB1>(an); an = dpp_add<0x4E>(an);

        const float r = sigf(g0 + ar + bhr);
        const float z = sigf(g1 + az + bhz);
        const float n = tanh_fast(g2 + r * (an + bhn));
        const float hn = (1.0f - z) * n + z * hprev;
        hprev = hn;

        if (c == 0) {
            sh[cur ^ 1][g] = hn;
            hsb[(size_t)t * HH + g] = hn;
        }
        g0 = n0; g1 = n1; g2 = n2;
        __syncthreads();  // single barrier: next step reads sh[cur^1]
    }
}

// ---------------- fallback: fully fused scan (if ws too small) -----------
__global__ __launch_bounds__(384, 2) void gru_scan_fused_kernel(
        const float* __restrict__ x, const float* __restrict__ W_ih,
        const float* __restrict__ b_ih, const float* __restrict__ W_hh,
        const float* __restrict__ b_hh, const float* __restrict__ W_out,
        const float* __restrict__ b_out, float* __restrict__ out) {
    __shared__ __align__(16) float sh[HH];
    __shared__ float sC[G3];
    __shared__ float sA[G3];
    __shared__ __align__(16) float sx[II];
    __shared__ __align__(16) float sWq[HH / 4][OO][4];
    __shared__ float sPart[4][OO];

    const int b = blockIdx.x;
    const int g = threadIdx.x;

    float whh[HH];
#pragma unroll
    for (int k = 0; k < HH; ++k) whh[k] = W_hh[g * HH + k];
    const float bh = b_hh[g];
    float wih[II];
#pragma unroll
    for (int k = 0; k < II; ++k) wih[k] = W_ih[g * II + k];
    const float bi = b_ih[g];
    float bo = (g < OO) ? b_out[g] : 0.0f;
    for (int i = g; i < OO * HH; i += 384) {
        int o = i / HH, k = i % HH;
        sWq[k >> 2][o][k & 3] = W_out[i];
    }
    if (g < HH) sh[g] = 0.0f;
    __syncthreads();

    const float4* sh4 = (const float4*)sh;
    const float* xb = x + (size_t)b * TT * II;
    float* outb = out + (size_t)b * TT * OO;
    const float4* sx4 = (const float4*)sx;
    for (int t = 0; t < TT; ++t) {
        if (g < II) sx[g] = xb[(size_t)t * II + g];
        __syncthreads();
        float a = bi, cc = bh;
#pragma unroll
        for (int k4 = 0; k4 < II / 4; ++k4) {
            float4 v = sx4[k4];
            a += wih[4*k4+0]*v.x + wih[4*k4+1]*v.y + wih[4*k4+2]*v.z + wih[4*k4+3]*v.w;
        }
#pragma unroll
        for (int k4 = 0; k4 < HH / 4; ++k4) {
            float4 v = sh4[k4];
            cc += whh[4*k4+0]*v.x + whh[4*k4+1]*v.y + whh[4*k4+2]*v.z + whh[4*k4+3]*v.w;
        }
        sA[g] = a; sC[g] = cc;
        __syncthreads();
        if (g < HH) {
            float r = sigf(sA[g] + sC[g]);
            float z = sigf(sA[HH + g] + sC[HH + g]);
            float n = tanh_fast(sA[2 * HH + g] + r * sC[2 * HH + g]);
            sh[g] = (1.0f - z) * n + z * sh[g];
        }
        __syncthreads();
        if (g < 256) {
            const int o = g & 63, part = g >> 6;
            float s = 0.0f;
#pragma unroll
            for (int k4 = 0; k4 < 8; ++k4) {
                const float4 wv = *(const float4*)sWq[part * 8 + k4][o];
                const float4 hv = sh4[part * 8 + k4];
                s += wv.x*hv.x + wv.y*hv.y + wv.z*hv.z + wv.w*hv.w;
            }
            sPart[part][o] = s;
        }
        __syncthreads();
        if (g < OO)
            outb[(size_t)t * OO + g] =
                bo + sPart[0][g] + sPart[1][g] + sPart[2][g] + sPart[3][g];
    }
}

// ---------------- out = hs @ W_out^T + b_out (parallel GEMM) -------------
__global__ __launch_bounds__(256) void gru_outproj_kernel(
        const float* __restrict__ hs, const float* __restrict__ W_out,
        const float* __restrict__ b_out, float* __restrict__ out) {
    __shared__ __align__(16) float sW[HH / 4][OO][4];
    __shared__ float sb[OO];
    const int tid = threadIdx.x;
    for (int i = tid; i < OO * HH; i += 256) {
        int o = i / HH, k = i % HH;
        sW[k >> 2][o][k & 3] = W_out[i];
    }
    if (tid < OO) sb[tid] = b_out[tid];
    __syncthreads();

    const int64_t row = (int64_t)blockIdx.x * 256 + tid;
    const float4* hrow = (const float4*)(hs + row * HH);
    float acc[OO];
#pragma unroll
    for (int o = 0; o < OO; ++o) acc[o] = 0.0f;
    for (int k4 = 0; k4 < HH / 4; ++k4) {
        float4 h4 = hrow[k4];
#pragma unroll
        for (int o = 0; o < OO; ++o) {
            const float4 w = *(const float4*)sW[k4][o];
            acc[o] += w.x*h4.x + w.y*h4.y + w.z*h4.z + w.w*h4.w;
        }
    }
    float* orow = out + row * OO;
#pragma unroll
    for (int o = 0; o < OO; ++o) orow[o] = sb[o] + acc[o];
}

extern "C" void kernel_launch(void* const* d_in, const int* in_sizes, int n_in,
                              void* d_out, int out_size, void* d_ws, size_t ws_size,
                              hipStream_t stream) {
    const float* x     = (const float*)d_in[0];
    const float* W_ih  = (const float*)d_in[1];
    const float* W_hh  = (const float*)d_in[2];
    const float* b_ih  = (const float*)d_in[3];
    const float* b_hh  = (const float*)d_in[4];
    const float* W_out = (const float*)d_in[5];
    const float* b_out = (const float*)d_in[6];
    float* out = (float*)d_out;

    const size_t need_gx = (size_t)BB * TT * G3 * sizeof(float);  // 201 MB
    const size_t need_hs = (size_t)BB * TT * HH * sizeof(float);  //  67 MB

    if (ws_size >= need_gx + need_hs) {
        float* gx = (float*)d_ws;
        float* hs = (float*)((char*)d_ws + need_gx);
        gru_gx_kernel<<<(BB * TT) / GX_ROWS, 768, 0, stream>>>(x, W_ih, b_ih, gx);
        gru_scan_kernel<<<BB, 512, 0, stream>>>(W_hh, b_hh, gx, hs);
        gru_outproj_kernel<<<(BB * TT) / 256, 256, 0, stream>>>(hs, W_out, b_out, out);
    } else {
        gru_scan_fused_kernel<<<BB, 384, 0, stream>>>(
            x, W_ih, b_ih, W_hh, b_hh, W_out, b_out, out);
    }
}

// Round 5
// 1728.001 us; speedup vs baseline: 1.0513x; 1.0513x over previous
//
#include <hip/hip_runtime.h>
#include <cstdint>
#include <cstddef>

#define HH 128   // hidden
#define II 64    // input
#define OO 64    // output
#define G3 384   // 3*H
#define BB 64    // batch
#define TT 2048  // time
#define GX_ROWS 32

__device__ __forceinline__ float sigf(float x) { return 1.0f / (1.0f + __expf(-x)); }
__device__ __forceinline__ float tanh_fast(float x) {
    x = fminf(20.0f, fmaxf(-20.0f, x));
    float e = __expf(2.0f * x);
    return (e - 1.0f) / (e + 1.0f);
}
__device__ __forceinline__ float dot4(float4 a, float4 b) {
    return a.x * b.x + a.y * b.y + a.z * b.z + a.w * b.w;
}

// Keep a value resident in a VGPR: opaque to the optimizer, so it cannot be
// rematerialized from memory inside the loop.
#define PIN(v)  asm volatile("" : "+v"(v))
#define PIN4(v) do { PIN((v).x); PIN((v).y); PIN((v).z); PIN((v).w); } while (0)

// Quad butterfly add via DPP quad_perm — VALU pipe.
// xor1 = quad_perm(1,0,3,2) = 0xB1 ; xor2 = quad_perm(2,3,0,1) = 0x4E.
template <int CTRL>
__device__ __forceinline__ float dpp_add(float x) {
    return x + __int_as_float(
        __builtin_amdgcn_mov_dpp(__float_as_int(x), CTRL, 0xF, 0xF, true));
}

// ---------------- gx = x @ W_ih^T + b_ih  (parallel GEMM) ----------------
__global__ __launch_bounds__(768) void gru_gx_kernel(
        const float* __restrict__ x, const float* __restrict__ W_ih,
        const float* __restrict__ b_ih, float* __restrict__ gx) {
    __shared__ __align__(16) float sx[GX_ROWS][II];
    const int tid = threadIdx.x;
    const int g = tid >> 1;
    const int kh = tid & 1;
    const int64_t row0 = (int64_t)blockIdx.x * GX_ROWS;

    float4 w4[8];
    {
        const float4* Wp = (const float4*)(W_ih + (size_t)g * II + kh * 32);
#pragma unroll
        for (int i = 0; i < 8; ++i) w4[i] = Wp[i];
    }
    const float bias = b_ih[g];

    for (int i = tid; i < GX_ROWS * II; i += 768)
        ((float*)sx)[i] = x[row0 * II + i];
    __syncthreads();

#pragma unroll 4
    for (int r = 0; r < GX_ROWS; ++r) {
        const float4* sx4 = (const float4*)sx[r] + kh * 8;
        float acc = 0.0f;
#pragma unroll
        for (int i = 0; i < 8; ++i) acc += dot4(w4[i], sx4[i]);
        acc += __shfl_xor(acc, 1);
        if (kh == 0) gx[(row0 + r) * (int64_t)G3 + g] = acc + bias;
    }
}

// ---------------- recurrent scan: one block per batch, 512 threads -------
// Thread (g, c): g = tid>>2 owns h-element g via gate rows {g, g+128, g+256};
// c = tid&3 is the k-chunk [32c, 32c+32). 96 weight floats/thread, PINNED.
// Grid is 64 blocks on 256 CUs -> exactly 1 block/CU -> only 2 waves/SIMD
// ever resident. amdgpu_waves_per_eu(2,2) tells the allocator that truth:
// VGPR budget 256/thread, so the pinned weights get real VGPRs instead of
// the AGPR spill R4 produced (VGPR_Count=80, VALUBusy doubled, no speedup).
__global__ __attribute__((amdgpu_flat_work_group_size(512, 512)))
__attribute__((amdgpu_waves_per_eu(2, 2)))
void gru_scan_kernel(
        const float* __restrict__ W_hh, const float* __restrict__ b_hh,
        const float* __restrict__ gx, float* __restrict__ hs) {
    __shared__ __align__(16) float sh[2][HH];

    const int b = blockIdx.x;
    const int tid = threadIdx.x;
    const int c = tid & 3;     // k-chunk
    const int g = tid >> 2;    // h element 0..127

    // rows g (reset), g+128 (update), g+256 (new), chunk [32c, 32c+32).
    // Pre-rotated by (j+2c)&7 so hot-loop reg indices are STATIC (R2 lesson)
    // and LDS reads land on disjoint banks across chunks.
    float4 wr[8], wz[8], wn[8];
    {
        const float4* Rr = (const float4*)(W_hh + (size_t)g * HH + c * 32);
        const float4* Rz = (const float4*)(W_hh + (size_t)(g + HH) * HH + c * 32);
        const float4* Rn = (const float4*)(W_hh + (size_t)(g + 2 * HH) * HH + c * 32);
#pragma unroll
        for (int j = 0; j < 8; ++j) {
            const int idx = (j + 2 * c) & 7;   // runtime -> ADDRESS only
            wr[j] = Rr[idx]; wz[j] = Rz[idx]; wn[j] = Rn[idx];
        }
    }
#pragma unroll
    for (int j = 0; j < 8; ++j) { PIN4(wr[j]); PIN4(wz[j]); PIN4(wn[j]); }

    const float bhr = b_hh[g];
    const float bhz = b_hh[HH + g];
    const float bhn = b_hh[2 * HH + g];

    if (tid < 2 * HH) ((float*)sh)[tid] = 0.0f;
    __syncthreads();

    const float* gxb = gx + (size_t)b * TT * G3;
    float* hsb = hs + (size_t)b * TT * HH;

    float g0 = gxb[g], g1 = gxb[HH + g], g2 = gxb[2 * HH + g];
    float hprev = 0.0f;

    for (int t = 0; t < TT; ++t) {
        const int cur = t & 1;
        // prefetch next step's gx (quad-uniform loads, L1/L2-served)
        float n0 = 0, n1 = 0, n2 = 0;
        if (t + 1 < TT) {
            const float* q = gxb + (size_t)(t + 1) * G3;
            n0 = q[g]; n1 = q[HH + g]; n2 = q[2 * HH + g];
        }

        const float4* shc = (const float4*)sh[cur] + c * 8;
        float ar = 0.0f, az = 0.0f, an = 0.0f;
#pragma unroll
        for (int j = 0; j < 8; ++j) {
            const float4 h4 = shc[(j + 2 * c) & 7];  // staggered: conflict-free
            ar += dot4(wr[j], h4);
            az += dot4(wz[j], h4);
            an += dot4(wn[j], h4);
        }
        // quad butterfly: all 4 lanes end with the full 128-k sum
        ar = dpp_add<0xB1>(ar); ar = dpp_add<0x4E>(ar);
        az = dpp_add<0xB1>(az); az = dpp_add<0x4E>(az);
        an = dpp_add<0xB1>(an); an = dpp_add<0x4E>(an);

        const float r = sigf(g0 + ar + bhr);
        const float z = sigf(g1 + az + bhz);
        const float n = tanh_fast(g2 + r * (an + bhn));
        const float hn = (1.0f - z) * n + z * hprev;
        hprev = hn;

        if (c == 0) {
            sh[cur ^ 1][g] = hn;
            hsb[(size_t)t * HH + g] = hn;
        }
        g0 = n0; g1 = n1; g2 = n2;
        __syncthreads();  // single barrier: next step reads sh[cur^1]
    }
}

// ---------------- fallback: fully fused scan (if ws too small) -----------
__global__ __launch_bounds__(384, 2) void gru_scan_fused_kernel(
        const float* __restrict__ x, const float* __restrict__ W_ih,
        const float* __restrict__ b_ih, const float* __restrict__ W_hh,
        const float* __restrict__ b_hh, const float* __restrict__ W_out,
        const float* __restrict__ b_out, float* __restrict__ out) {
    __shared__ __align__(16) float sh[HH];
    __shared__ float sC[G3];
    __shared__ float sA[G3];
    __shared__ __align__(16) float sx[II];
    __shared__ __align__(16) float sWq[HH / 4][OO][4];
    __shared__ float sPart[4][OO];

    const int b = blockIdx.x;
    const int g = threadIdx.x;

    float whh[HH];
#pragma unroll
    for (int k = 0; k < HH; ++k) whh[k] = W_hh[g * HH + k];
    const float bh = b_hh[g];
    float wih[II];
#pragma unroll
    for (int k = 0; k < II; ++k) wih[k] = W_ih[g * II + k];
    const float bi = b_ih[g];
    float bo = (g < OO) ? b_out[g] : 0.0f;
    for (int i = g; i < OO * HH; i += 384) {
        int o = i / HH, k = i % HH;
        sWq[k >> 2][o][k & 3] = W_out[i];
    }
    if (g < HH) sh[g] = 0.0f;
    __syncthreads();

    const float4* sh4 = (const float4*)sh;
    const float* xb = x + (size_t)b * TT * II;
    float* outb = out + (size_t)b * TT * OO;
    const float4* sx4 = (const float4*)sx;
    for (int t = 0; t < TT; ++t) {
        if (g < II) sx[g] = xb[(size_t)t * II + g];
        __syncthreads();
        float a = bi, cc = bh;
#pragma unroll
        for (int k4 = 0; k4 < II / 4; ++k4) {
            float4 v = sx4[k4];
            a += wih[4*k4+0]*v.x + wih[4*k4+1]*v.y + wih[4*k4+2]*v.z + wih[4*k4+3]*v.w;
        }
#pragma unroll
        for (int k4 = 0; k4 < HH / 4; ++k4) {
            float4 v = sh4[k4];
            cc += whh[4*k4+0]*v.x + whh[4*k4+1]*v.y + whh[4*k4+2]*v.z + whh[4*k4+3]*v.w;
        }
        sA[g] = a; sC[g] = cc;
        __syncthreads();
        if (g < HH) {
            float r = sigf(sA[g] + sC[g]);
            float z = sigf(sA[HH + g] + sC[HH + g]);
            float n = tanh_fast(sA[2 * HH + g] + r * sC[2 * HH + g]);
            sh[g] = (1.0f - z) * n + z * sh[g];
        }
        __syncthreads();
        if (g < 256) {
            const int o = g & 63, part = g >> 6;
            float s = 0.0f;
#pragma unroll
            for (int k4 = 0; k4 < 8; ++k4) {
                const float4 wv = *(const float4*)sWq[part * 8 + k4][o];
                const float4 hv = sh4[part * 8 + k4];
                s += wv.x*hv.x + wv.y*hv.y + wv.z*hv.z + wv.w*hv.w;
            }
            sPart[part][o] = s;
        }
        __syncthreads();
        if (g < OO)
            outb[(size_t)t * OO + g] =
                bo + sPart[0][g] + sPart[1][g] + sPart[2][g] + sPart[3][g];
    }
}

// ---------------- out = hs @ W_out^T + b_out (parallel GEMM) -------------
__global__ __launch_bounds__(256) void gru_outproj_kernel(
        const float* __restrict__ hs, const float* __restrict__ W_out,
        const float* __restrict__ b_out, float* __restrict__ out) {
    __shared__ __align__(16) float sW[HH / 4][OO][4];
    __shared__ float sb[OO];
    const int tid = threadIdx.x;
    for (int i = tid; i < OO * HH; i += 256) {
        int o = i / HH, k = i % HH;
        sW[k >> 2][o][k & 3] = W_out[i];
    }
    if (tid < OO) sb[tid] = b_out[tid];
    __syncthreads();

    const int64_t row = (int64_t)blockIdx.x * 256 + tid;
    const float4* hrow = (const float4*)(hs + row * HH);
    float acc[OO];
#pragma unroll
    for (int o = 0; o < OO; ++o) acc[o] = 0.0f;
    for (int k4 = 0; k4 < HH / 4; ++k4) {
        float4 h4 = hrow[k4];
#pragma unroll
        for (int o = 0; o < OO; ++o) {
            const float4 w = *(const float4*)sW[k4][o];
            acc[o] += w.x*h4.x + w.y*h4.y + w.z*h4.z + w.w*h4.w;
        }
    }
    float* orow = out + row * OO;
#pragma unroll
    for (int o = 0; o < OO; ++o) orow[o] = sb[o] + acc[o];
}

extern "C" void kernel_launch(void* const* d_in, const int* in_sizes, int n_in,
                              void* d_out, int out_size, void* d_ws, size_t ws_size,
                              hipStream_t stream) {
    const float* x     = (const float*)d_in[0];
    const float* W_ih  = (const float*)d_in[1];
    const float* W_hh  = (const float*)d_in[2];
    const float* b_ih  = (const float*)d_in[3];
    const float* b_hh  = (const float*)d_in[4];
    const float* W_out = (const float*)d_in[5];
    const float* b_out = (const float*)d_in[6];
    float* out = (float*)d_out;

    const size_t need_gx = (size_t)BB * TT * G3 * sizeof(float);  // 201 MB
    const size_t need_hs = (size_t)BB * TT * HH * sizeof(float);  //  67 MB

    if (ws_size >= need_gx + need_hs) {
        float* gx = (float*)d_ws;
        float* hs = (float*)((char*)d_ws + need_gx);
        gru_gx_kernel<<<(BB * TT) / GX_ROWS, 768, 0, stream>>>(x, W_ih, b_ih, gx);
        gru_scan_kernel<<<BB, 512, 0, stream>>>(W_hh, b_hh, gx, hs);
        gru_outproj_kernel<<<(BB * TT) / 256, 256, 0, stream>>>(hs, W_out, b_out, out);
    } else {
        gru_scan_fused_kernel<<<BB, 384, 0, stream>>>(
            x, W_ih, b_ih, W_hh, b_hh, W_out, b_out, out);
    }
}